// Round 1
// baseline (20311.124 us; speedup 1.0000x reference)
//
#include <hip/hip_runtime.h>
#include <math.h>

#define NBLK 256
#define NTHR 512
#define Bsz  32
#define Hsz  512
#define Vsz  32000
#define BH   (Bsz*Hsz)

struct Args {
  const float* h0_init;  // [2,B,H]
  const float* emb;      // [V,E]
  const float* Wih0; const float* Whh0; const float* bih0; const float* bhh0;
  const float* Wih1; const float* Whh1; const float* bih1; const float* bhh1;
  const float* Wout; const float* bout;
  const int*   maxn;
  float* out;                  // [B*T] tokens-as-float, then [2*B*H] h_t
  float* hbuf;                 // ws: 4*BH floats (h0 A/B, h1 A/B)
  unsigned long long* packed;  // 32 entries, stride 16 ull (128B apart)
  unsigned* bar;               // [0]=counter, [1]=generation
};

// ---- grid barrier: counter + generation, agent-scope atomics ----
__device__ __forceinline__ void gridbar(unsigned* cnt, unsigned* gen){
  __threadfence();   // publish this thread's global writes device-wide
  __syncthreads();
  if (threadIdx.x == 0){
    unsigned g = __hip_atomic_load(gen, __ATOMIC_RELAXED, __HIP_MEMORY_SCOPE_AGENT);
    unsigned old = __hip_atomic_fetch_add(cnt, 1u, __ATOMIC_ACQ_REL, __HIP_MEMORY_SCOPE_AGENT);
    if (old == (unsigned)(NBLK - 1)){
      __hip_atomic_store(cnt, 0u, __ATOMIC_RELAXED, __HIP_MEMORY_SCOPE_AGENT);
      __hip_atomic_fetch_add(gen, 1u, __ATOMIC_RELEASE, __HIP_MEMORY_SCOPE_AGENT);
    } else {
      while (__hip_atomic_load(gen, __ATOMIC_ACQUIRE, __HIP_MEMORY_SCOPE_AGENT) == g){
        __builtin_amdgcn_s_sleep(1);
      }
    }
  }
  __syncthreads();
}

__device__ __forceinline__ float red8(float v){
  v += __shfl_xor(v, 1); v += __shfl_xor(v, 2); v += __shfl_xor(v, 4);
  return v;
}

__device__ __forceinline__ float dot4acc(float4 w, float4 x, float acc){
  return fmaf(w.x,x.x, fmaf(w.y,x.y, fmaf(w.z,x.z, fmaf(w.w,x.w, acc))));
}

// one oct (8 lanes) computes one (b,j) output of a GRU layer
__device__ __forceinline__ void gru_oct(
    const float* xrow, const float* hrow,
    const float* Wih, const float* Whh,
    const float* bih, const float* bhh,
    int j, int lane8, float* hout)
{
  const float* wir = Wih + (size_t)j * Hsz;   // rows j, j+512, j+1024 (E==H==512)
  const float* whr = Whh + (size_t)j * Hsz;
  float ar=0.f, az=0.f, an=0.f, hr=0.f, hz=0.f, hn=0.f;
  #pragma unroll 4
  for (int i = 0; i < 16; ++i){
    int k = i*32 + lane8*4;
    float4 xv = *(const float4*)(xrow + k);
    float4 hv = *(const float4*)(hrow + k);
    ar = dot4acc(*(const float4*)(wir + k),            xv, ar);
    az = dot4acc(*(const float4*)(wir + 512*512 + k),  xv, az);
    an = dot4acc(*(const float4*)(wir + 2*512*512 + k),xv, an);
    hr = dot4acc(*(const float4*)(whr + k),            hv, hr);
    hz = dot4acc(*(const float4*)(whr + 512*512 + k),  hv, hz);
    hn = dot4acc(*(const float4*)(whr + 2*512*512 + k),hv, hn);
  }
  ar = red8(ar); az = red8(az); an = red8(an);
  hr = red8(hr); hz = red8(hz); hn = red8(hn);
  if (lane8 == 0){
    float r = 1.f/(1.f + expf(-(ar + bih[j]       + hr + bhh[j])));
    float z = 1.f/(1.f + expf(-(az + bih[Hsz+j]   + hz + bhh[Hsz+j])));
    float n = tanhf(an + bih[2*Hsz+j] + r*(hn + bhh[2*Hsz+j]));
    hout[j] = (1.f - z)*n + z*hrow[j];
  }
}

__global__ __launch_bounds__(NTHR, 1) void decoder_kernel(Args a){
  const int tid = threadIdx.x;
  const int bid = blockIdx.x;
  const int T = a.maxn[0];
  __shared__ unsigned long long bestq[NTHR/4];

  for (int t = 0; t < T; ++t){
    const int wsel = t & 1;
    const float* h0prev = (t == 0) ? a.h0_init        : (a.hbuf + ((t-1)&1)*BH);
    const float* h1prev = (t == 0) ? (a.h0_init + BH) : (a.hbuf + 2*BH + ((t-1)&1)*BH);
    float* h0new = a.hbuf + wsel*BH;
    float* h1new = a.hbuf + 2*BH + wsel*BH;

    // ---- Phase A: embedding gather + GRU layer 0 ----
    {
      int oct = tid >> 3, lane8 = tid & 7;
      int b = oct & 31, jj = oct >> 5;
      int j = bid*2 + jj;
      int tok;
      if (t == 0) tok = 1;  // SOS
      else        tok = (int)(~(unsigned)(a.packed[b*16] & 0xffffffffULL));
      const float* xrow = a.emb + (size_t)tok * Hsz;
      gru_oct(xrow, h0prev + b*Hsz, a.Wih0, a.Whh0, a.bih0, a.bhh0,
              j, lane8, h0new + b*Hsz);
    }
    gridbar(a.bar, a.bar + 1);

    // ---- Phase B: harvest token t-1 + zero packed; GRU layer 1 ----
    if (bid == 0 && tid < Bsz){
      unsigned long long p = a.packed[tid*16];
      if (t > 0){
        int tok = (int)(~(unsigned)(p & 0xffffffffULL));
        a.out[tid*T + (t-1)] = (float)tok;
      }
      a.packed[tid*16] = 0ULL;
    }
    {
      int oct = tid >> 3, lane8 = tid & 7;
      int b = oct & 31, jj = oct >> 5;
      int j = bid*2 + jj;
      gru_oct(h0new + b*Hsz, h1prev + b*Hsz, a.Wih1, a.Whh1, a.bih1, a.bhh1,
              j, lane8, h1new + b*Hsz);
    }
    gridbar(a.bar, a.bar + 1);

    // ---- Phase C: logits + argmax (250 blocks x 128 rows) ----
    if (bid < 250){
      int quad = tid >> 2, l4 = tid & 3;
      int b = quad & 31, hi = quad >> 5;
      const float* hb = h1new + b*Hsz;
      float bestv = -3.4e38f; int besti = 0;
      int vbase = bid*128 + hi;
      for (int tt = 0; tt < 16; ++tt){
        int va = vbase + tt*8;
        int vb = va + 4;
        const float* wa = a.Wout + (size_t)va * Hsz;
        const float* wb = a.Wout + (size_t)vb * Hsz;
        float aa = 0.f, ab = 0.f;
        #pragma unroll 4
        for (int i = 0; i < 32; ++i){
          int k = i*16 + l4*4;
          float4 h4 = *(const float4*)(hb + k);
          aa = dot4acc(*(const float4*)(wa + k), h4, aa);
          ab = dot4acc(*(const float4*)(wb + k), h4, ab);
        }
        aa += __shfl_xor(aa,1); aa += __shfl_xor(aa,2);
        ab += __shfl_xor(ab,1); ab += __shfl_xor(ab,2);
        if (l4 == 0){
          float la = aa + a.bout[va];
          float lb = ab + a.bout[vb];
          if (la > bestv){ bestv = la; besti = va; }
          if (lb > bestv){ bestv = lb; besti = vb; }
        }
      }
      if (l4 == 0){
        unsigned u = __float_as_uint(bestv);
        unsigned key = (u & 0x80000000u) ? ~u : (u | 0x80000000u);
        bestq[quad] = ((unsigned long long)key << 32) | (unsigned)(~(unsigned)besti);
      }
      __syncthreads();
      if (tid < Bsz){
        unsigned long long m = bestq[tid];
        unsigned long long c;
        c = bestq[tid+32]; m = (c > m) ? c : m;
        c = bestq[tid+64]; m = (c > m) ? c : m;
        c = bestq[tid+96]; m = (c > m) ? c : m;
        atomicMax(&a.packed[tid*16], m);
      }
    }
    gridbar(a.bar, a.bar + 1);
  }

  // ---- final harvest + final hidden-state copy ----
  if (bid == 0 && tid < Bsz){
    unsigned long long p = a.packed[tid*16];
    int tok = (int)(~(unsigned)(p & 0xffffffffULL));
    a.out[tid*T + (T-1)] = (float)tok;
  }
  int wf = (T-1) & 1;
  int e = bid*NTHR + tid;
  if (e < BH){
    a.out[Bsz*T + e]      = a.hbuf[wf*BH + e];          // layer 0 final state
    a.out[Bsz*T + BH + e] = a.hbuf[2*BH + wf*BH + e];   // layer 1 final state
  }
}

extern "C" void kernel_launch(void* const* d_in, const int* in_sizes, int n_in,
                              void* d_out, int out_size, void* d_ws, size_t ws_size,
                              hipStream_t stream){
  Args a;
  a.h0_init = (const float*)d_in[0];
  a.emb  = (const float*)d_in[1];
  a.Wih0 = (const float*)d_in[2];
  a.Whh0 = (const float*)d_in[3];
  a.bih0 = (const float*)d_in[4];
  a.bhh0 = (const float*)d_in[5];
  a.Wih1 = (const float*)d_in[6];
  a.Whh1 = (const float*)d_in[7];
  a.bih1 = (const float*)d_in[8];
  a.bhh1 = (const float*)d_in[9];
  a.Wout = (const float*)d_in[10];
  a.bout = (const float*)d_in[11];
  a.maxn = (const int*)d_in[12];
  a.out  = (float*)d_out;
  a.hbuf = (float*)d_ws;
  char* wsb = (char*)d_ws;
  a.packed = (unsigned long long*)(wsb + (size_t)4*BH*sizeof(float));
  a.bar    = (unsigned*)(wsb + (size_t)4*BH*sizeof(float) + 4096);

  // ws is poisoned 0xAA before every call: zero packed-argmax slots + barrier state
  hipMemsetAsync(wsb + (size_t)4*BH*sizeof(float), 0, 4096 + 256, stream);

  void* params[] = { &a };
  hipLaunchCooperativeKernel((void*)decoder_kernel, dim3(NBLK), dim3(NTHR),
                             params, 0, stream);
}

// Round 2
// 16788.947 us; speedup vs baseline: 1.2098x; 1.2098x over previous
//
#include <hip/hip_runtime.h>
#include <math.h>

#define NBLK 256
#define NTHR 512
#define Bsz  32
#define Hsz  512
#define Vsz  32000
#define BH   (Bsz*Hsz)

struct Args {
  const float* h0_init;  // [2,B,H]
  const float* emb;      // [V,E]
  const float* Wih0; const float* Whh0; const float* bih0; const float* bhh0;
  const float* Wih1; const float* Whh1; const float* bih1; const float* bhh1;
  const float* Wout; const float* bout;
  const int*   maxn;
  float* out;                  // [B*T] tokens-as-float, then [2*B*H] h_t
  float* hbuf;                 // ws: 4*BH floats (h0 A/B, h1 A/B)
  unsigned long long* packed;  // 32 entries, stride 16 ull (128B apart)
  unsigned* bar;               // [0]=counter, [1]=generation
};

// ---- grid barrier: counter + generation, agent-scope atomics ----
__device__ __forceinline__ void gridbar(unsigned* cnt, unsigned* gen){
  __threadfence();
  __syncthreads();
  if (threadIdx.x == 0){
    unsigned g = __hip_atomic_load(gen, __ATOMIC_RELAXED, __HIP_MEMORY_SCOPE_AGENT);
    unsigned old = __hip_atomic_fetch_add(cnt, 1u, __ATOMIC_ACQ_REL, __HIP_MEMORY_SCOPE_AGENT);
    if (old == (unsigned)(NBLK - 1)){
      __hip_atomic_store(cnt, 0u, __ATOMIC_RELAXED, __HIP_MEMORY_SCOPE_AGENT);
      __hip_atomic_fetch_add(gen, 1u, __ATOMIC_RELEASE, __HIP_MEMORY_SCOPE_AGENT);
    } else {
      while (__hip_atomic_load(gen, __ATOMIC_ACQUIRE, __HIP_MEMORY_SCOPE_AGENT) == g){
        __builtin_amdgcn_s_sleep(1);
      }
    }
  }
  __syncthreads();
}

__device__ __forceinline__ float red8(float v){
  v += __shfl_xor(v, 1); v += __shfl_xor(v, 2); v += __shfl_xor(v, 4);
  return v;
}

__device__ __forceinline__ float dot4acc(float4 w, float4 x, float acc){
  return fmaf(w.x,x.x, fmaf(w.y,x.y, fmaf(w.z,x.z, fmaf(w.w,x.w, acc))));
}

// one oct (8 lanes) computes one (b,j) output of a GRU layer
__device__ __forceinline__ void gru_oct(
    const float* xrow, const float* hrow,
    const float* Wih, const float* Whh,
    const float* bih, const float* bhh,
    int j, int lane8, float* hout)
{
  const float* wir = Wih + (size_t)j * Hsz;
  const float* whr = Whh + (size_t)j * Hsz;
  float ar=0.f, az=0.f, an=0.f, hr=0.f, hz=0.f, hn=0.f;
  #pragma unroll 4
  for (int i = 0; i < 16; ++i){
    int k = i*32 + lane8*4;
    float4 xv = *(const float4*)(xrow + k);
    float4 hv = *(const float4*)(hrow + k);
    ar = dot4acc(*(const float4*)(wir + k),            xv, ar);
    az = dot4acc(*(const float4*)(wir + 512*512 + k),  xv, az);
    an = dot4acc(*(const float4*)(wir + 2*512*512 + k),xv, an);
    hr = dot4acc(*(const float4*)(whr + k),            hv, hr);
    hz = dot4acc(*(const float4*)(whr + 512*512 + k),  hv, hz);
    hn = dot4acc(*(const float4*)(whr + 2*512*512 + k),hv, hn);
  }
  ar = red8(ar); az = red8(az); an = red8(an);
  hr = red8(hr); hz = red8(hz); hn = red8(hn);
  if (lane8 == 0){
    float r = 1.f/(1.f + expf(-(ar + bih[j]       + hr + bhh[j])));
    float z = 1.f/(1.f + expf(-(az + bih[Hsz+j]   + hz + bhh[Hsz+j])));
    float n = tanhf(an + bih[2*Hsz+j] + r*(hn + bhh[2*Hsz+j]));
    hout[j] = (1.f - z)*n + z*hrow[j];
  }
}

__global__ __launch_bounds__(NTHR, 2) void decoder_kernel(Args a){
  const int tid = threadIdx.x;
  const int bid = blockIdx.x;
  const int T = a.maxn[0];
  // argmax scratch: lbest[rg][b]  (32 row-groups x 32 batch), 8KB
  __shared__ unsigned long long lbest[32*32];

  for (int t = 0; t < T; ++t){
    const int wsel = t & 1;
    const float* h0prev = (t == 0) ? a.h0_init        : (a.hbuf + ((t-1)&1)*BH);
    const float* h1prev = (t == 0) ? (a.h0_init + BH) : (a.hbuf + 2*BH + ((t-1)&1)*BH);
    float* h0new = a.hbuf + wsel*BH;
    float* h1new = a.hbuf + 2*BH + wsel*BH;

    // ---- Phase A: embedding gather + GRU layer 0 ----
    {
      int oct = tid >> 3, lane8 = tid & 7;
      int b = oct & 31, jj = oct >> 5;
      int j = bid*2 + jj;
      int tok;
      if (t == 0) tok = 1;  // SOS
      else        tok = (int)(~(unsigned)(a.packed[b*16] & 0xffffffffULL));
      const float* xrow = a.emb + (size_t)tok * Hsz;
      gru_oct(xrow, h0prev + b*Hsz, a.Wih0, a.Whh0, a.bih0, a.bhh0,
              j, lane8, h0new + b*Hsz);
    }
    gridbar(a.bar, a.bar + 1);

    // ---- Phase B: harvest token t-1 + zero packed; GRU layer 1 ----
    if (bid == 0 && tid < Bsz){
      unsigned long long p = a.packed[tid*16];
      if (t > 0){
        int tok = (int)(~(unsigned)(p & 0xffffffffULL));
        a.out[tid*T + (t-1)] = (float)tok;
      }
      a.packed[tid*16] = 0ULL;
    }
    {
      int oct = tid >> 3, lane8 = tid & 7;
      int b = oct & 31, jj = oct >> 5;
      int j = bid*2 + jj;
      gru_oct(h0new + b*Hsz, h1prev + b*Hsz, a.Wih1, a.Whh1, a.bih1, a.bhh1,
              j, lane8, h1new + b*Hsz);
    }
    gridbar(a.bar, a.bar + 1);

    // ---- Phase C: logits + argmax ----
    // 250 blocks x 128 rows. Each quad owns a 4-row x 8-batch register tile,
    // k split over the 4 lanes (contiguous 64B per quad -> coalesced).
    // W line reuse: each W load instr is shared by 4 b-groups (was 32 quads).
    if (bid < 250){
      const int quad = tid >> 2;       // 0..127
      const int l4   = tid & 3;
      const int rg   = quad & 31;      // row-group 0..31
      const int bg   = quad >> 5;      // b-group 0..3 (8 b each)
      const int rowbase = bid*128 + rg*4;
      const float* wr = a.Wout + (size_t)rowbase * Hsz;
      const float* hb = h1new + (size_t)bg * 8 * Hsz;

      float acc[4][8];
      #pragma unroll
      for (int s = 0; s < 4; ++s)
        #pragma unroll
        for (int j = 0; j < 8; ++j) acc[s][j] = 0.f;

      #pragma unroll 2
      for (int i = 0; i < 32; ++i){
        const int k = i*16 + l4*4;
        float4 wv[4], hv[8];
        #pragma unroll
        for (int s = 0; s < 4; ++s)
          wv[s] = *(const float4*)(wr + (size_t)s*Hsz + k);
        #pragma unroll
        for (int j = 0; j < 8; ++j)
          hv[j] = *(const float4*)(hb + (size_t)j*Hsz + k);
        #pragma unroll
        for (int s = 0; s < 4; ++s)
          #pragma unroll
          for (int j = 0; j < 8; ++j)
            acc[s][j] = dot4acc(wv[s], hv[j], acc[s][j]);
      }

      // quad-level k reduction: all 4 lanes end with full sums
      #pragma unroll
      for (int s = 0; s < 4; ++s)
        #pragma unroll
        for (int j = 0; j < 8; ++j){
          float v = acc[s][j];
          v += __shfl_xor(v, 1);
          v += __shfl_xor(v, 2);
          acc[s][j] = v;
        }

      if (l4 == 0){
        float4 bv = *(const float4*)(a.bout + rowbase);
        float bb[4] = {bv.x, bv.y, bv.z, bv.w};
        #pragma unroll
        for (int j = 0; j < 8; ++j){
          float best = -3.4e38f; int bi = rowbase;
          #pragma unroll
          for (int s = 0; s < 4; ++s){
            float lv = acc[s][j] + bb[s];
            if (lv > best){ best = lv; bi = rowbase + s; }
          }
          unsigned u = __float_as_uint(best);
          unsigned key = (u & 0x80000000u) ? ~u : (u | 0x80000000u);
          lbest[rg*32 + bg*8 + j] =
              ((unsigned long long)key << 32) | (unsigned)(~(unsigned)bi);
        }
      }
      __syncthreads();
      if (tid < Bsz){
        unsigned long long m = lbest[tid];
        #pragma unroll 4
        for (int r = 1; r < 32; ++r){
          unsigned long long c = lbest[r*32 + tid];
          m = (c > m) ? c : m;
        }
        atomicMax(&a.packed[tid*16], m);
      }
    }
    gridbar(a.bar, a.bar + 1);
  }

  // ---- final harvest + final hidden-state copy ----
  if (bid == 0 && tid < Bsz){
    unsigned long long p = a.packed[tid*16];
    int tok = (int)(~(unsigned)(p & 0xffffffffULL));
    a.out[tid*T + (T-1)] = (float)tok;
  }
  int wf = (T-1) & 1;
  int e = bid*NTHR + tid;
  if (e < BH){
    a.out[Bsz*T + e]      = a.hbuf[wf*BH + e];
    a.out[Bsz*T + BH + e] = a.hbuf[2*BH + wf*BH + e];
  }
}

extern "C" void kernel_launch(void* const* d_in, const int* in_sizes, int n_in,
                              void* d_out, int out_size, void* d_ws, size_t ws_size,
                              hipStream_t stream){
  Args a;
  a.h0_init = (const float*)d_in[0];
  a.emb  = (const float*)d_in[1];
  a.Wih0 = (const float*)d_in[2];
  a.Whh0 = (const float*)d_in[3];
  a.bih0 = (const float*)d_in[4];
  a.bhh0 = (const float*)d_in[5];
  a.Wih1 = (const float*)d_in[6];
  a.Whh1 = (const float*)d_in[7];
  a.bih1 = (const float*)d_in[8];
  a.bhh1 = (const float*)d_in[9];
  a.Wout = (const float*)d_in[10];
  a.bout = (const float*)d_in[11];
  a.maxn = (const int*)d_in[12];
  a.out  = (float*)d_out;
  a.hbuf = (float*)d_ws;
  char* wsb = (char*)d_ws;
  a.packed = (unsigned long long*)(wsb + (size_t)4*BH*sizeof(float));
  a.bar    = (unsigned*)(wsb + (size_t)4*BH*sizeof(float) + 4096);

  // ws is poisoned 0xAA before every call: zero packed-argmax slots + barrier state
  hipMemsetAsync(wsb + (size_t)4*BH*sizeof(float), 0, 4096 + 256, stream);

  void* params[] = { &a };
  hipLaunchCooperativeKernel((void*)decoder_kernel, dim3(NBLK), dim3(NTHR),
                             params, 0, stream);
}

// Round 3
// 6686.538 us; speedup vs baseline: 3.0376x; 2.5109x over previous
//
#include <hip/hip_runtime.h>
#include <math.h>

#define NBLK 256
#define NTHR 512
#define Bsz  32
#define Hsz  512
#define Vsz  32000
#define BH   (Bsz*Hsz)
#define LDP  516   // LDS row stride (floats): 512 + 4 pad -> conflict-free oct reads

struct Args {
  const float* h0_init;  // [2,B,H]
  const float* emb;      // [V,E]
  const float* Wih0; const float* Whh0; const float* bih0; const float* bhh0;
  const float* Wih1; const float* Whh1; const float* bih1; const float* bhh1;
  const float* Wout; const float* bout;
  const int*   maxn;
  float* out;                  // [B*T] tokens-as-float, then [2*B*H] h_t
  float* hbuf;                 // ws: 4*BH floats (h0 A/B, h1 A/B)
  unsigned long long* packed;  // 32 entries, stride 16 ull (128B apart)
  unsigned* bar;               // [0]=counter, [1]=generation
};

// ---- coherent (L3-point, cache-bypass) accessors: NO cache invalidates ----
__device__ __forceinline__ unsigned long long cload8(const void* p){
  return __hip_atomic_load((const unsigned long long*)p,
                           __ATOMIC_RELAXED, __HIP_MEMORY_SCOPE_AGENT);
}
__device__ __forceinline__ void cstore4(float* p, float v){
  __hip_atomic_store(p, v, __ATOMIC_RELAXED, __HIP_MEMORY_SCOPE_AGENT);
}
__device__ __forceinline__ void cstore8(void* p, unsigned long long v){
  __hip_atomic_store((unsigned long long*)p, v,
                     __ATOMIC_RELAXED, __HIP_MEMORY_SCOPE_AGENT);
}

// ---- grid barrier: relaxed atomics only (no agent acquire/release fences).
// __syncthreads() drains each wave's vmcnt (compiler emits s_waitcnt vmcnt(0)
// before s_barrier), so all coherent stores of this block are at L3 before
// the leader signals. Explicit waitcnt orders cnt-reset before gen-bump.
__device__ __forceinline__ void gridbar(unsigned* cnt, unsigned* gen){
  __syncthreads();
  if (threadIdx.x == 0){
    asm volatile("s_waitcnt vmcnt(0)" ::: "memory");
    unsigned g = __hip_atomic_load(gen, __ATOMIC_RELAXED, __HIP_MEMORY_SCOPE_AGENT);
    unsigned old = __hip_atomic_fetch_add(cnt, 1u, __ATOMIC_RELAXED, __HIP_MEMORY_SCOPE_AGENT);
    if (old == (unsigned)(NBLK - 1)){
      __hip_atomic_store(cnt, 0u, __ATOMIC_RELAXED, __HIP_MEMORY_SCOPE_AGENT);
      asm volatile("s_waitcnt vmcnt(0)" ::: "memory");
      __hip_atomic_fetch_add(gen, 1u, __ATOMIC_RELAXED, __HIP_MEMORY_SCOPE_AGENT);
    } else {
      while (__hip_atomic_load(gen, __ATOMIC_RELAXED, __HIP_MEMORY_SCOPE_AGENT) == g){
        __builtin_amdgcn_s_sleep(2);
      }
    }
  }
  __syncthreads();
}

// stage 32x512 floats (64KB) global -> LDS with row stride LDP, coherent 8B loads
__device__ __forceinline__ void stage_h(const float* g, float* s, int tid){
  const unsigned long long* gd = (const unsigned long long*)g;
  #pragma unroll
  for (int n = 0; n < 16; ++n){
    int idx = n*512 + tid;          // ull index 0..8191
    int row = idx >> 8;             // 256 ull per row
    int col = idx & 255;
    unsigned long long v = __hip_atomic_load(gd + idx, __ATOMIC_RELAXED,
                                             __HIP_MEMORY_SCOPE_AGENT);
    *(unsigned long long*)(s + row*LDP + col*2) = v;
  }
}

__device__ __forceinline__ float red8(float v){
  v += __shfl_xor(v, 1); v += __shfl_xor(v, 2); v += __shfl_xor(v, 4);
  return v;
}

__device__ __forceinline__ float dot4acc(float4 w, float4 x, float acc){
  return fmaf(w.x,x.x, fmaf(w.y,x.y, fmaf(w.z,x.z, fmaf(w.w,x.w, acc))));
}

// one oct (8 lanes) computes one (b,j) output of a GRU layer.
// xrow: contiguous 512 floats (global or LDS row); hrow: LDS row.
__device__ __forceinline__ void gru_oct(
    const float* xrow, const float* hrow,
    const float* Wih, const float* Whh,
    const float* bih, const float* bhh,
    int j, int lane8, float* hout_g)
{
  const float* wir = Wih + (size_t)j * Hsz;
  const float* whr = Whh + (size_t)j * Hsz;
  float ar=0.f, az=0.f, an=0.f, hr=0.f, hz=0.f, hn=0.f;
  #pragma unroll 4
  for (int i = 0; i < 16; ++i){
    int k = i*32 + lane8*4;
    float4 xv = *(const float4*)(xrow + k);
    float4 hv = *(const float4*)(hrow + k);
    ar = dot4acc(*(const float4*)(wir + k),            xv, ar);
    az = dot4acc(*(const float4*)(wir + 512*512 + k),  xv, az);
    an = dot4acc(*(const float4*)(wir + 2*512*512 + k),xv, an);
    hr = dot4acc(*(const float4*)(whr + k),            hv, hr);
    hz = dot4acc(*(const float4*)(whr + 512*512 + k),  hv, hz);
    hn = dot4acc(*(const float4*)(whr + 2*512*512 + k),hv, hn);
  }
  ar = red8(ar); az = red8(az); an = red8(an);
  hr = red8(hr); hz = red8(hz); hn = red8(hn);
  if (lane8 == 0){
    float r = 1.f/(1.f + expf(-(ar + bih[j]       + hr + bhh[j])));
    float z = 1.f/(1.f + expf(-(az + bih[Hsz+j]   + hz + bhh[Hsz+j])));
    float n = tanhf(an + bih[2*Hsz+j] + r*(hn + bhh[2*Hsz+j]));
    cstore4(hout_g, (1.f - z)*n + z*hrow[j]);
  }
}

__global__ __launch_bounds__(NTHR, 1) void decoder_kernel(Args a){
  const int tid = threadIdx.x;
  const int bid = blockIdx.x;
  const int T = a.maxn[0];

  __shared__ float shA[Bsz*LDP];                 // 66 KB
  __shared__ float shB[Bsz*LDP];                 // 66 KB
  __shared__ unsigned long long lbest[32*32];    // 8 KB
  __shared__ int sh_tok[Bsz];

  for (int t = 0; t < T; ++t){
    const int wsel = t & 1;
    const float* h0prev = (t == 0) ? a.h0_init        : (a.hbuf + ((t-1)&1)*BH);
    const float* h1prev = (t == 0) ? (a.h0_init + BH) : (a.hbuf + 2*BH + ((t-1)&1)*BH);
    float* h0new = a.hbuf + wsel*BH;
    float* h1new = a.hbuf + 2*BH + wsel*BH;

    // ---- Phase A: stage h0prev + tokens; embedding gather + GRU layer 0 ----
    stage_h(h0prev, shA, tid);
    if (tid < Bsz){
      int tok;
      if (t == 0) tok = 1;   // SOS
      else        tok = (int)(~(unsigned)(cload8(&a.packed[tid*16]) & 0xffffffffULL));
      sh_tok[tid] = tok;
    }
    __syncthreads();
    {
      int oct = tid >> 3, lane8 = tid & 7;
      int b = oct & 31, jj = oct >> 5;
      int j = bid*2 + jj;
      const float* xrow = a.emb + (size_t)sh_tok[b] * Hsz;  // cached path (read-only)
      gru_oct(xrow, shA + b*LDP, a.Wih0, a.Whh0, a.bih0, a.bhh0,
              j, lane8, h0new + b*Hsz + j);
    }
    gridbar(a.bar, a.bar + 1);

    // ---- Phase B: harvest token t-1 + zero packed; GRU layer 1 ----
    if (bid == 0 && tid < Bsz){
      if (t > 0){
        unsigned long long p = cload8(&a.packed[tid*16]);
        int tok = (int)(~(unsigned)(p & 0xffffffffULL));
        a.out[tid*T + (t-1)] = (float)tok;
      }
      cstore8(&a.packed[tid*16], 0ULL);
    }
    stage_h(h0new, shA, tid);
    stage_h(h1prev, shB, tid);
    __syncthreads();
    {
      int oct = tid >> 3, lane8 = tid & 7;
      int b = oct & 31, jj = oct >> 5;
      int j = bid*2 + jj;
      gru_oct(shA + b*LDP, shB + b*LDP, a.Wih1, a.Whh1, a.bih1, a.bhh1,
              j, lane8, h1new + b*Hsz + j);
    }
    gridbar(a.bar, a.bar + 1);

    // ---- Phase C: logits + argmax (250 blocks x 128 rows) ----
    if (bid < 250){
      stage_h(h1new, shA, tid);
      __syncthreads();

      const int quad = tid >> 2;       // 0..127
      const int l4   = tid & 3;
      const int rg   = quad & 31;      // row-group
      const int bg   = quad >> 5;      // b-group (8 b each)
      const int rowbase = bid*128 + rg*4;
      const float* wr = a.Wout + (size_t)rowbase * Hsz;  // cached path
      const float* hb = shA + bg*8*LDP;

      float acc[4][8];
      #pragma unroll
      for (int s = 0; s < 4; ++s)
        #pragma unroll
        for (int j = 0; j < 8; ++j) acc[s][j] = 0.f;

      #pragma unroll 2
      for (int i = 0; i < 32; ++i){
        const int k = i*16 + l4*4;
        float4 wv[4], hv[8];
        #pragma unroll
        for (int s = 0; s < 4; ++s)
          wv[s] = *(const float4*)(wr + (size_t)s*Hsz + k);
        #pragma unroll
        for (int j = 0; j < 8; ++j)
          hv[j] = *(const float4*)(hb + j*LDP + k);   // LDS broadcast, conflict-free
        #pragma unroll
        for (int s = 0; s < 4; ++s)
          #pragma unroll
          for (int j = 0; j < 8; ++j)
            acc[s][j] = dot4acc(wv[s], hv[j], acc[s][j]);
      }

      #pragma unroll
      for (int s = 0; s < 4; ++s)
        #pragma unroll
        for (int j = 0; j < 8; ++j){
          float v = acc[s][j];
          v += __shfl_xor(v, 1);
          v += __shfl_xor(v, 2);
          acc[s][j] = v;
        }

      if (l4 == 0){
        float4 bv = *(const float4*)(a.bout + rowbase);
        float bb[4] = {bv.x, bv.y, bv.z, bv.w};
        #pragma unroll
        for (int j = 0; j < 8; ++j){
          float best = -3.4e38f; int bi = rowbase;
          #pragma unroll
          for (int s = 0; s < 4; ++s){
            float lv = acc[s][j] + bb[s];
            if (lv > best){ best = lv; bi = rowbase + s; }
          }
          unsigned u = __float_as_uint(best);
          unsigned key = (u & 0x80000000u) ? ~u : (u | 0x80000000u);
          lbest[rg*32 + bg*8 + j] =
              ((unsigned long long)key << 32) | (unsigned)(~(unsigned)bi);
        }
      }
      __syncthreads();
      if (tid < Bsz){
        unsigned long long m = lbest[tid];
        #pragma unroll 4
        for (int r = 1; r < 32; ++r){
          unsigned long long c = lbest[r*32 + tid];
          m = (c > m) ? c : m;
        }
        atomicMax(&a.packed[tid*16], m);   // relaxed device-scope RMW at L3
      }
    }
    gridbar(a.bar, a.bar + 1);
  }

  // ---- final harvest + final hidden-state copy ----
  if (bid == 0 && tid < Bsz){
    unsigned long long p = cload8(&a.packed[tid*16]);
    int tok = (int)(~(unsigned)(p & 0xffffffffULL));
    a.out[tid*T + (T-1)] = (float)tok;
  }
  int wf = (T-1) & 1;
  int e = bid*NTHR + tid;           // ull index
  if (e < BH/2){
    unsigned long long v0 = cload8((const unsigned long long*)(a.hbuf + (size_t)wf*BH) + e);
    unsigned long long v1 = cload8((const unsigned long long*)(a.hbuf + 2*(size_t)BH + (size_t)wf*BH) + e);
    *((unsigned long long*)(a.out + Bsz*T) + e)      = v0;
    *((unsigned long long*)(a.out + Bsz*T + BH) + e) = v1;
  }
}

extern "C" void kernel_launch(void* const* d_in, const int* in_sizes, int n_in,
                              void* d_out, int out_size, void* d_ws, size_t ws_size,
                              hipStream_t stream){
  Args a;
  a.h0_init = (const float*)d_in[0];
  a.emb  = (const float*)d_in[1];
  a.Wih0 = (const float*)d_in[2];
  a.Whh0 = (const float*)d_in[3];
  a.bih0 = (const float*)d_in[4];
  a.bhh0 = (const float*)d_in[5];
  a.Wih1 = (const float*)d_in[6];
  a.Whh1 = (const float*)d_in[7];
  a.bih1 = (const float*)d_in[8];
  a.bhh1 = (const float*)d_in[9];
  a.Wout = (const float*)d_in[10];
  a.bout = (const float*)d_in[11];
  a.maxn = (const int*)d_in[12];
  a.out  = (float*)d_out;
  a.hbuf = (float*)d_ws;
  char* wsb = (char*)d_ws;
  a.packed = (unsigned long long*)(wsb + (size_t)4*BH*sizeof(float));
  a.bar    = (unsigned*)(wsb + (size_t)4*BH*sizeof(float) + 4096);

  // ws is poisoned 0xAA before every call: zero packed-argmax slots + barrier state
  hipMemsetAsync(wsb + (size_t)4*BH*sizeof(float), 0, 4096 + 256, stream);

  void* params[] = { &a };
  hipLaunchCooperativeKernel((void*)decoder_kernel, dim3(NBLK), dim3(NTHR),
                             params, 0, stream);
}

// Round 4
// 5398.264 us; speedup vs baseline: 3.7625x; 1.2386x over previous
//
#include <hip/hip_runtime.h>
#include <math.h>

#define NBLK 256
#define NTHR 512
#define Bsz  32
#define Hsz  512
#define Vsz  32000
#define BH   (Bsz*Hsz)
#define LDP  516   // LDS row stride (floats): 512 + 4 pad

struct Args {
  const float* h0_init;  // [2,B,H]
  const float* emb;      // [V,E]
  const float* Wih0; const float* Whh0; const float* bih0; const float* bhh0;
  const float* Wih1; const float* Whh1; const float* bih1; const float* bhh1;
  const float* Wout; const float* bout;
  const int*   maxn;
  float* out;                  // [B*T] tokens-as-float, then [2*B*H] h_t
  float* hbuf;                 // ws: h0 [BH], h1 [BH] (single-buffered)
  unsigned long long* packed;  // 32 entries, stride 16 ull (128B apart)
  unsigned* bar;               // tree barrier: 17 words at 128B stride
};

// ---- coherent (L3-point) accessors: relaxed agent scope, NO cache invalidates ----
__device__ __forceinline__ unsigned long long cload8(const void* p){
  return __hip_atomic_load((const unsigned long long*)p,
                           __ATOMIC_RELAXED, __HIP_MEMORY_SCOPE_AGENT);
}
__device__ __forceinline__ void cstore4(float* p, float v){
  __hip_atomic_store(p, v, __ATOMIC_RELAXED, __HIP_MEMORY_SCOPE_AGENT);
}
__device__ __forceinline__ void cstore8(void* p, unsigned long long v){
  __hip_atomic_store((unsigned long long*)p, v,
                     __ATOMIC_RELAXED, __HIP_MEMORY_SCOPE_AGENT);
}

// ---- 2-level tree barrier: 8 groups x 32 blocks -> root -> 8 gen words.
// All hot words on separate 128B lines; pollers poll only their group's gen.
__device__ __forceinline__ void gridbar(unsigned* bar, int bid){
  __syncthreads();   // per-wave s_waitcnt vmcnt(0) before s_barrier (compiler)
  if (threadIdx.x == 0){
    asm volatile("s_waitcnt vmcnt(0)" ::: "memory");
    const int g = bid & 7;
    unsigned* gcnt = bar + g*32;
    unsigned* root = bar + 8*32;
    unsigned* gen  = bar + (9+g)*32;
    unsigned mygen = __hip_atomic_load(gen, __ATOMIC_RELAXED, __HIP_MEMORY_SCOPE_AGENT);
    unsigned go = __hip_atomic_fetch_add(gcnt, 1u, __ATOMIC_RELAXED, __HIP_MEMORY_SCOPE_AGENT);
    if (go == 31u){
      unsigned ro = __hip_atomic_fetch_add(root, 1u, __ATOMIC_RELAXED, __HIP_MEMORY_SCOPE_AGENT);
      if (ro == 7u){
        // all 256 arrived: reset counters, then (ordered) bump all gens
        #pragma unroll
        for (int i = 0; i < 8; ++i)
          __hip_atomic_store(bar + i*32, 0u, __ATOMIC_RELAXED, __HIP_MEMORY_SCOPE_AGENT);
        __hip_atomic_store(root, 0u, __ATOMIC_RELAXED, __HIP_MEMORY_SCOPE_AGENT);
        asm volatile("s_waitcnt vmcnt(0)" ::: "memory");
        #pragma unroll
        for (int i = 0; i < 8; ++i)
          __hip_atomic_fetch_add(bar + (9+i)*32, 1u, __ATOMIC_RELAXED, __HIP_MEMORY_SCOPE_AGENT);
      }
    }
    while (__hip_atomic_load(gen, __ATOMIC_RELAXED, __HIP_MEMORY_SCOPE_AGENT) == mygen){
      __builtin_amdgcn_s_sleep(4);
    }
  }
  __syncthreads();
}

// stage 32x512 floats (64KB) global -> LDS with row stride LDP, coherent 8B loads
__device__ __forceinline__ void stage_h(const float* g, float* s, int tid){
  const unsigned long long* gd = (const unsigned long long*)g;
  #pragma unroll
  for (int n = 0; n < 16; ++n){
    int idx = n*512 + tid;          // ull index 0..8191
    int row = idx >> 8;             // 256 ull per row
    int col = idx & 255;
    unsigned long long v = __hip_atomic_load(gd + idx, __ATOMIC_RELAXED,
                                             __HIP_MEMORY_SCOPE_AGENT);
    *(unsigned long long*)(s + row*LDP + col*2) = v;
  }
}

__device__ __forceinline__ float red8(float v){
  v += __shfl_xor(v, 1); v += __shfl_xor(v, 2); v += __shfl_xor(v, 4);
  return v;
}

__device__ __forceinline__ float dot4acc(float4 w, float4 x, float acc){
  return fmaf(w.x,x.x, fmaf(w.y,x.y, fmaf(w.z,x.z, fmaf(w.w,x.w, acc))));
}

// one oct (8 lanes) computes one (b,j) output of a GRU layer.
__device__ __forceinline__ void gru_oct(
    const float* xrow, const float* hrow,
    const float* Wih, const float* Whh,
    const float* bih, const float* bhh,
    int j, int lane8, float* hout_g)
{
  const float* wir = Wih + (size_t)j * Hsz;
  const float* whr = Whh + (size_t)j * Hsz;
  float ar=0.f, az=0.f, an=0.f, hr=0.f, hz=0.f, hn=0.f;
  #pragma unroll 4
  for (int i = 0; i < 16; ++i){
    int k = i*32 + lane8*4;
    float4 xv = *(const float4*)(xrow + k);
    float4 hv = *(const float4*)(hrow + k);
    ar = dot4acc(*(const float4*)(wir + k),            xv, ar);
    az = dot4acc(*(const float4*)(wir + 512*512 + k),  xv, az);
    an = dot4acc(*(const float4*)(wir + 2*512*512 + k),xv, an);
    hr = dot4acc(*(const float4*)(whr + k),            hv, hr);
    hz = dot4acc(*(const float4*)(whr + 512*512 + k),  hv, hz);
    hn = dot4acc(*(const float4*)(whr + 2*512*512 + k),hv, hn);
  }
  ar = red8(ar); az = red8(az); an = red8(an);
  hr = red8(hr); hz = red8(hz); hn = red8(hn);
  if (lane8 == 0){
    float r = 1.f/(1.f + expf(-(ar + bih[j]       + hr + bhh[j])));
    float z = 1.f/(1.f + expf(-(az + bih[Hsz+j]   + hz + bhh[Hsz+j])));
    float n = tanhf(an + bih[2*Hsz+j] + r*(hn + bhh[2*Hsz+j]));
    cstore4(hout_g, (1.f - z)*n + z*hrow[j]);
  }
}

__global__ __launch_bounds__(NTHR, 1) void decoder_kernel(Args a){
  const int tid = threadIdx.x;
  const int bid = blockIdx.x;
  const int T = a.maxn[0];
  float* h0g = a.hbuf;        // global h0 (single-buffered)
  float* h1g = a.hbuf + BH;   // global h1

  __shared__ float shA[Bsz*LDP];                 // h0 mirror (66 KB)
  __shared__ float shB[Bsz*LDP];                 // h1 mirror (66 KB)
  __shared__ unsigned long long lbest[32*32];    // 8 KB
  __shared__ int sh_tok[Bsz];

  for (int t = 0; t < T; ++t){
    // ---- Phase A: GRU layer 0.  h0prev already in shA (staged in B(t-1)). ----
    if (t == 0) stage_h(a.h0_init, shA, tid);
    if (tid < Bsz){
      int tok;
      if (t == 0) tok = 1;   // SOS
      else        tok = (int)(~(unsigned)(cload8(&a.packed[tid*16]) & 0xffffffffULL));
      sh_tok[tid] = tok;
    }
    __syncthreads();
    {
      int oct = tid >> 3, lane8 = tid & 7;
      int b = oct & 31, jj = oct >> 5;
      int j = bid*2 + jj;
      const float* xrow = a.emb + (size_t)sh_tok[b] * Hsz;  // cached path
      gru_oct(xrow, shA + b*LDP, a.Wih0, a.Whh0, a.bih0, a.bhh0,
              j, lane8, h0g + b*Hsz + j);
    }
    gridbar(a.bar, bid);

    // ---- Phase B: harvest token t-1 + zero packed; GRU layer 1 ----
    if (bid == 0 && tid < Bsz){
      if (t > 0){
        unsigned long long p = cload8(&a.packed[tid*16]);
        int tok = (int)(~(unsigned)(p & 0xffffffffULL));
        a.out[tid*T + (t-1)] = (float)tok;
      }
      cstore8(&a.packed[tid*16], 0ULL);
    }
    stage_h(h0g, shA, tid);                       // fresh h0new -> shA
    if (t == 0) stage_h(a.h0_init + BH, shB, tid); // h1prev only at t=0
    __syncthreads();
    {
      int oct = tid >> 3, lane8 = tid & 7;
      int b = oct & 31, jj = oct >> 5;
      int j = bid*2 + jj;
      gru_oct(shA + b*LDP, shB + b*LDP, a.Wih1, a.Whh1, a.bih1, a.bhh1,
              j, lane8, h1g + b*Hsz + j);
    }
    gridbar(a.bar, bid);

    // ---- Phase C: stage h1new -> shB (ALL blocks, persists as next h1prev);
    //      logits + argmax on 250 blocks x 128 rows ----
    stage_h(h1g, shB, tid);
    __syncthreads();
    if (bid < 250){
      const int quad = tid >> 2;       // 0..127
      const int l4   = tid & 3;
      const int rg   = quad & 31;      // row-group
      const int bg   = quad >> 5;      // b-group (8 b each)
      const int rowbase = bid*128 + rg*4;
      const float* wr = a.Wout + (size_t)rowbase * Hsz;  // cached path
      const float* hb = shB + bg*8*LDP;

      float acc[4][8];
      #pragma unroll
      for (int s = 0; s < 4; ++s)
        #pragma unroll
        for (int j = 0; j < 8; ++j) acc[s][j] = 0.f;

      #pragma unroll 2
      for (int i = 0; i < 32; ++i){
        const int k = i*16 + l4*4;
        float4 wv[4], hv[8];
        #pragma unroll
        for (int s = 0; s < 4; ++s)
          wv[s] = *(const float4*)(wr + (size_t)s*Hsz + k);
        #pragma unroll
        for (int j = 0; j < 8; ++j)
          hv[j] = *(const float4*)(hb + j*LDP + k);
        #pragma unroll
        for (int s = 0; s < 4; ++s)
          #pragma unroll
          for (int j = 0; j < 8; ++j)
            acc[s][j] = dot4acc(wv[s], hv[j], acc[s][j]);
      }

      #pragma unroll
      for (int s = 0; s < 4; ++s)
        #pragma unroll
        for (int j = 0; j < 8; ++j){
          float v = acc[s][j];
          v += __shfl_xor(v, 1);
          v += __shfl_xor(v, 2);
          acc[s][j] = v;
        }

      if (l4 == 0){
        float4 bv = *(const float4*)(a.bout + rowbase);
        float bb[4] = {bv.x, bv.y, bv.z, bv.w};
        #pragma unroll
        for (int j = 0; j < 8; ++j){
          float best = -3.4e38f; int bi = rowbase;
          #pragma unroll
          for (int s = 0; s < 4; ++s){
            float lv = acc[s][j] + bb[s];
            if (lv > best){ best = lv; bi = rowbase + s; }
          }
          unsigned u = __float_as_uint(best);
          unsigned key = (u & 0x80000000u) ? ~u : (u | 0x80000000u);
          lbest[rg*32 + bg*8 + j] =
              ((unsigned long long)key << 32) | (unsigned)(~(unsigned)bi);
        }
      }
      __syncthreads();
      if (tid < Bsz){
        unsigned long long m = lbest[tid];
        #pragma unroll 4
        for (int r = 1; r < 32; ++r){
          unsigned long long c = lbest[r*32 + tid];
          m = (c > m) ? c : m;
        }
        atomicMax(&a.packed[tid*16], m);   // device-scope RMW at L3
      }
    }
    gridbar(a.bar, bid);
  }

  // ---- final harvest + final hidden-state copy ----
  if (bid == 0 && tid < Bsz){
    unsigned long long p = cload8(&a.packed[tid*16]);
    int tok = (int)(~(unsigned)(p & 0xffffffffULL));
    a.out[tid*T + (T-1)] = (float)tok;
  }
  int e = bid*NTHR + tid;           // ull index
  if (e < BH/2){
    unsigned long long v0 = cload8((const unsigned long long*)h0g + e);
    unsigned long long v1 = cload8((const unsigned long long*)h1g + e);
    *((unsigned long long*)(a.out + Bsz*T) + e)      = v0;
    *((unsigned long long*)(a.out + Bsz*T + BH) + e) = v1;
  }
}

extern "C" void kernel_launch(void* const* d_in, const int* in_sizes, int n_in,
                              void* d_out, int out_size, void* d_ws, size_t ws_size,
                              hipStream_t stream){
  Args a;
  a.h0_init = (const float*)d_in[0];
  a.emb  = (const float*)d_in[1];
  a.Wih0 = (const float*)d_in[2];
  a.Whh0 = (const float*)d_in[3];
  a.bih0 = (const float*)d_in[4];
  a.bhh0 = (const float*)d_in[5];
  a.Wih1 = (const float*)d_in[6];
  a.Whh1 = (const float*)d_in[7];
  a.bih1 = (const float*)d_in[8];
  a.bhh1 = (const float*)d_in[9];
  a.Wout = (const float*)d_in[10];
  a.bout = (const float*)d_in[11];
  a.maxn = (const int*)d_in[12];
  a.out  = (float*)d_out;
  a.hbuf = (float*)d_ws;
  char* wsb = (char*)d_ws;
  a.packed = (unsigned long long*)(wsb + (size_t)2*BH*sizeof(float));
  a.bar    = (unsigned*)(wsb + (size_t)2*BH*sizeof(float) + 4096);

  // ws is poisoned 0xAA before every call: zero packed slots + barrier state
  hipMemsetAsync(wsb + (size_t)2*BH*sizeof(float), 0, 8192, stream);

  void* params[] = { &a };
  hipLaunchCooperativeKernel((void*)decoder_kernel, dim3(NBLK), dim3(NTHR),
                             params, 0, stream);
}

// Round 5
// 4343.347 us; speedup vs baseline: 4.6764x; 1.2429x over previous
//
#include <hip/hip_runtime.h>
#include <math.h>

#define NBLK 256
#define NTHR 512
#define Bsz  32
#define Hsz  512
#define Vsz  32000
#define BH   (Bsz*Hsz)
#define LDP  516         // LDS row stride (floats): 512 + 4 pad
#define CBLK 250         // blocks doing logits (128 rows each)
#define EPS  0.0045f     // bf16 dot-product error coefficient (provable bound w/ margin)

// ---- ws layout (bytes) ----
#define WS_HBUF   0            // 2*BH floats = 131072
#define WS_PACKED 131072       // 32 x 128B (ull key64 per b)
#define WS_PLB    135168       // 32 x 128B (u32 lb-key per b)
#define WS_BAR    139264       // 17 x 128B tree barrier
#define WS_WPACK  143360       // 250*8*16*1024 = 32768000 (bf16 B-frags)
#define WS_WNORM  32911360     // 32000 floats (EPS * ||w_n||2)
#define WS_NEEDED 33039360

typedef short short8 __attribute__((ext_vector_type(8)));
typedef float f32x4  __attribute__((ext_vector_type(4)));

struct Args {
  const float* h0_init;
  const float* emb;
  const float* Wih0; const float* Whh0; const float* bih0; const float* bhh0;
  const float* Wih1; const float* Whh1; const float* bih1; const float* bhh1;
  const float* Wout; const float* bout;
  const int*   maxn;
  float* out;
  float* hbuf;                 // [2*BH] h0,h1 (single-buffered)
  unsigned long long* packed;  // final fp32-key argmax per b (128B stride)
  unsigned* plb;               // per-b max lower-bound key (u32, 128B stride)
  unsigned* bar;
  const unsigned* wpack;       // bf16 B-fragment packed Wout
  const float* wnormE;         // EPS * ||bf16(w_n)||_2
};

// ---- bf16 helpers (consistent RNE everywhere) ----
__device__ __forceinline__ unsigned short bf16_rne(float f){
  unsigned u = __float_as_uint(f);
  unsigned r = u + 0x7FFFu + ((u >> 16) & 1u);
  return (unsigned short)(r >> 16);
}
__device__ __forceinline__ float bf16v(float f){   // value after bf16 RNE rounding
  unsigned u = ((unsigned)bf16_rne(f)) << 16;
  return __uint_as_float(u);
}
__device__ __forceinline__ unsigned short bf16_ru(float f){  // round toward +inf
  unsigned u = __float_as_uint(f);
  unsigned t = u >> 16;
  if (!(u & 0x80000000u)) { if (u & 0xFFFFu) t++; }  // positive: bump; negative: trunc
  return (unsigned short)t;
}
__device__ __forceinline__ unsigned key32(float f){  // monotone float->uint
  unsigned u = __float_as_uint(f);
  return (u & 0x80000000u) ? ~u : (u | 0x80000000u);
}

// ---- coherent (L3-point) accessors ----
__device__ __forceinline__ unsigned long long cload8(const void* p){
  return __hip_atomic_load((const unsigned long long*)p,
                           __ATOMIC_RELAXED, __HIP_MEMORY_SCOPE_AGENT);
}
__device__ __forceinline__ unsigned cload4u(const unsigned* p){
  return __hip_atomic_load(p, __ATOMIC_RELAXED, __HIP_MEMORY_SCOPE_AGENT);
}
__device__ __forceinline__ void cstore4(float* p, float v){
  __hip_atomic_store(p, v, __ATOMIC_RELAXED, __HIP_MEMORY_SCOPE_AGENT);
}
__device__ __forceinline__ void cstore4u(unsigned* p, unsigned v){
  __hip_atomic_store(p, v, __ATOMIC_RELAXED, __HIP_MEMORY_SCOPE_AGENT);
}
__device__ __forceinline__ void cstore8(void* p, unsigned long long v){
  __hip_atomic_store((unsigned long long*)p, v,
                     __ATOMIC_RELAXED, __HIP_MEMORY_SCOPE_AGENT);
}

// ---- 2-level tree barrier (relaxed, contention-sharded) ----
__device__ __forceinline__ void gridbar(unsigned* bar, int bid){
  __syncthreads();
  if (threadIdx.x == 0){
    asm volatile("s_waitcnt vmcnt(0)" ::: "memory");
    const int g = bid & 7;
    unsigned* gcnt = bar + g*32;
    unsigned* root = bar + 8*32;
    unsigned* gen  = bar + (9+g)*32;
    unsigned mygen = __hip_atomic_load(gen, __ATOMIC_RELAXED, __HIP_MEMORY_SCOPE_AGENT);
    unsigned go = __hip_atomic_fetch_add(gcnt, 1u, __ATOMIC_RELAXED, __HIP_MEMORY_SCOPE_AGENT);
    if (go == 31u){
      unsigned ro = __hip_atomic_fetch_add(root, 1u, __ATOMIC_RELAXED, __HIP_MEMORY_SCOPE_AGENT);
      if (ro == 7u){
        #pragma unroll
        for (int i = 0; i < 8; ++i)
          __hip_atomic_store(bar + i*32, 0u, __ATOMIC_RELAXED, __HIP_MEMORY_SCOPE_AGENT);
        __hip_atomic_store(root, 0u, __ATOMIC_RELAXED, __HIP_MEMORY_SCOPE_AGENT);
        asm volatile("s_waitcnt vmcnt(0)" ::: "memory");
        #pragma unroll
        for (int i = 0; i < 8; ++i)
          __hip_atomic_fetch_add(bar + (9+i)*32, 1u, __ATOMIC_RELAXED, __HIP_MEMORY_SCOPE_AGENT);
      }
    }
    while (__hip_atomic_load(gen, __ATOMIC_RELAXED, __HIP_MEMORY_SCOPE_AGENT) == mygen){
      __builtin_amdgcn_s_sleep(1);
    }
  }
  __syncthreads();
}

// stage 32x512 floats global -> LDS (row stride LDP), coherent 8B loads
__device__ __forceinline__ void stage_h(const float* g, float* s, int tid){
  const unsigned long long* gd = (const unsigned long long*)g;
  #pragma unroll
  for (int n = 0; n < 16; ++n){
    int idx = n*512 + tid;
    int row = idx >> 8;
    int col = idx & 255;
    unsigned long long v = __hip_atomic_load(gd + idx, __ATOMIC_RELAXED,
                                             __HIP_MEMORY_SCOPE_AGENT);
    *(unsigned long long*)(s + row*LDP + col*2) = v;
  }
}

__device__ __forceinline__ float red8(float v){
  v += __shfl_xor(v, 1); v += __shfl_xor(v, 2); v += __shfl_xor(v, 4);
  return v;
}
__device__ __forceinline__ float dot4acc(float4 w, float4 x, float acc){
  return fmaf(w.x,x.x, fmaf(w.y,x.y, fmaf(w.z,x.z, fmaf(w.w,x.w, acc))));
}

__device__ __forceinline__ void gru_oct(
    const float* xrow, const float* hrow,
    const float* Wih, const float* Whh,
    const float* bih, const float* bhh,
    int j, int lane8, float* hout_g)
{
  const float* wir = Wih + (size_t)j * Hsz;
  const float* whr = Whh + (size_t)j * Hsz;
  float ar=0.f, az=0.f, an=0.f, hr=0.f, hz=0.f, hn=0.f;
  #pragma unroll 4
  for (int i = 0; i < 16; ++i){
    int k = i*32 + lane8*4;
    float4 xv = *(const float4*)(xrow + k);
    float4 hv = *(const float4*)(hrow + k);
    ar = dot4acc(*(const float4*)(wir + k),            xv, ar);
    az = dot4acc(*(const float4*)(wir + 512*512 + k),  xv, az);
    an = dot4acc(*(const float4*)(wir + 2*512*512 + k),xv, an);
    hr = dot4acc(*(const float4*)(whr + k),            hv, hr);
    hz = dot4acc(*(const float4*)(whr + 512*512 + k),  hv, hz);
    hn = dot4acc(*(const float4*)(whr + 2*512*512 + k),hv, hn);
  }
  ar = red8(ar); az = red8(az); an = red8(an);
  hr = red8(hr); hz = red8(hz); hn = red8(hn);
  if (lane8 == 0){
    float r = 1.f/(1.f + expf(-(ar + bih[j]       + hr + bhh[j])));
    float z = 1.f/(1.f + expf(-(az + bih[Hsz+j]   + hz + bhh[Hsz+j])));
    float n = tanhf(an + bih[2*Hsz+j] + r*(hn + bhh[2*Hsz+j]));
    cstore4(hout_g, (1.f - z)*n + z*hrow[j]);
  }
}

// ================= repack: Wout fp32 -> bf16 B-fragments + row norms =================
// B-frag for mfma_f32_16x16x32_bf16: lane holds B[k=(lane>>4)*8+j][n=lane&15].
// wpack[(bid*8+g)*16+c] is a 1KB chunk: lane*16B, rows n = bid*128+g*16+(lane&15),
// k = c*32 + (lane>>4)*8 + j.
__global__ __launch_bounds__(512) void repack_kernel(const float* __restrict__ Wout,
                                                     unsigned* __restrict__ wpack,
                                                     float* __restrict__ wnormE){
  const int rb = blockIdx.x;            // 0..249
  const int g = threadIdx.x >> 6;       // wave
  const int lane = threadIdx.x & 63;
  const int n = rb*128 + g*16 + (lane & 15);
  const int kq = (lane >> 4) * 8;
  float sumsq = 0.f;
  for (int c = 0; c < 16; ++c){
    const float* p = Wout + (size_t)n*512 + c*32 + kq;
    float4 f0 = *(const float4*)p;
    float4 f1 = *(const float4*)(p + 4);
    unsigned short s0 = bf16_rne(f0.x), s1 = bf16_rne(f0.y),
                   s2 = bf16_rne(f0.z), s3 = bf16_rne(f0.w),
                   s4 = bf16_rne(f1.x), s5 = bf16_rne(f1.y),
                   s6 = bf16_rne(f1.z), s7 = bf16_rne(f1.w);
    float v;
    v = __uint_as_float(((unsigned)s0)<<16); sumsq += v*v;
    v = __uint_as_float(((unsigned)s1)<<16); sumsq += v*v;
    v = __uint_as_float(((unsigned)s2)<<16); sumsq += v*v;
    v = __uint_as_float(((unsigned)s3)<<16); sumsq += v*v;
    v = __uint_as_float(((unsigned)s4)<<16); sumsq += v*v;
    v = __uint_as_float(((unsigned)s5)<<16); sumsq += v*v;
    v = __uint_as_float(((unsigned)s6)<<16); sumsq += v*v;
    v = __uint_as_float(((unsigned)s7)<<16); sumsq += v*v;
    uint4 u;
    u.x = (unsigned)s0 | ((unsigned)s1<<16);
    u.y = (unsigned)s2 | ((unsigned)s3<<16);
    u.z = (unsigned)s4 | ((unsigned)s5<<16);
    u.w = (unsigned)s6 | ((unsigned)s7<<16);
    *(uint4*)(wpack + (size_t)(((rb*8+g)*16 + c))*256 + lane*4) = u;
  }
  sumsq += __shfl_xor(sumsq, 16);
  sumsq += __shfl_xor(sumsq, 32);
  if (lane < 16) wnormE[n] = EPS * sqrtf(sumsq);
}

// ================= main cooperative kernel (MFMA path) =================
__global__ __launch_bounds__(NTHR, 1) void decoder_kernel(Args a){
  const int tid = threadIdx.x;
  const int bid = blockIdx.x;
  const int wave = tid >> 6;
  const int lane = tid & 63;
  const int T = a.maxn[0];
  float* h0g = a.hbuf;
  float* h1g = a.hbuf + BH;

  __shared__ float shA[Bsz*LDP];                 // h0 mirror
  __shared__ float shB[Bsz*LDP];                 // h1 mirror (fp32, used for rescore)
  __shared__ unsigned af[16*64*4];               // A-fragments, one m-tile (16 KB)
  __shared__ unsigned long long ubq8[128*8];     // packed bf16 upper bounds (8 KB)
  __shared__ unsigned lbmaxL[32];
  __shared__ unsigned maxlbL[32];
  __shared__ float hnormL[32];
  __shared__ int sh_tok[Bsz];
  __shared__ int candCnt;
  __shared__ int candList[512];
  unsigned short* ubq16 = (unsigned short*)ubq8;

  for (int t = 0; t < T; ++t){
    // ---- Phase A: GRU layer 0 (h0prev in shA from previous B; t=0: stage) ----
    if (t == 0) stage_h(a.h0_init, shA, tid);
    if (tid < Bsz){
      int tok;
      if (t == 0) tok = 1;
      else        tok = (int)(~(unsigned)(cload8(&a.packed[tid*16]) & 0xffffffffULL));
      sh_tok[tid] = tok;
    }
    __syncthreads();
    {
      int oct = tid >> 3, lane8 = tid & 7;
      int b = oct & 31, jj = oct >> 5;
      int j = bid*2 + jj;
      const float* xrow = a.emb + (size_t)sh_tok[b] * Hsz;
      gru_oct(xrow, shA + b*LDP, a.Wih0, a.Whh0, a.bih0, a.bhh0,
              j, lane8, h0g + b*Hsz + j);
    }
    gridbar(a.bar, bid);

    // ---- Phase B: harvest token t-1, zero packed/plb; GRU layer 1 ----
    if (bid == 0 && tid < Bsz){
      if (t > 0){
        unsigned long long p = cload8(&a.packed[tid*16]);
        int tok = (int)(~(unsigned)(p & 0xffffffffULL));
        a.out[tid*T + (t-1)] = (float)tok;
      }
      cstore8(&a.packed[tid*16], 0ULL);
      cstore4u(&a.plb[tid*32], 0u);
    }
    stage_h(h0g, shA, tid);
    if (t == 0) stage_h(a.h0_init + BH, shB, tid);
    __syncthreads();
    {
      int oct = tid >> 3, lane8 = tid & 7;
      int b = oct & 31, jj = oct >> 5;
      int j = bid*2 + jj;
      gru_oct(shA + b*LDP, shB + b*LDP, a.Wih1, a.Whh1, a.bih1, a.bhh1,
              j, lane8, h1g + b*Hsz + j);
    }
    gridbar(a.bar, bid);

    // ---- Phase C: stage h1new->shB (all blocks); bf16 MFMA logits + bounds ----
    stage_h(h1g, shB, tid);
    if (tid < 32) lbmaxL[tid] = 0u;
    __syncthreads();
    if (bid < CBLK){
      // h-norms of the bf16-rounded h (octs 0..31)
      if (tid < 256){
        int b = tid >> 3, lane8 = tid & 7;
        float s = 0.f;
        #pragma unroll
        for (int i = 0; i < 8; ++i){
          const float* p = shB + b*LDP + i*64 + lane8*8;
          #pragma unroll
          for (int q = 0; q < 8; ++q){ float v = bf16v(p[q]); s = fmaf(v, v, s); }
        }
        s = red8(s);
        if (lane8 == 0) hnormL[b] = sqrtf(s);
      }
      // preload this wave's 16 B-fragments (held across both m-tiles)
      const unsigned* wbase = a.wpack + (size_t)((bid*8 + wave)*16)*256 + lane*4;
      short8 bw[16];
      #pragma unroll
      for (int c = 0; c < 16; ++c)
        bw[c] = *(const short8*)(wbase + c*256);

      f32x4 accs[2];
      #pragma unroll
      for (int mt = 0; mt < 2; ++mt){
        // build A-fragments for m-tile mt into af[]
        #pragma unroll
        for (int it = 0; it < 8; ++it){
          int d = it*512 + tid;
          int c = d >> 8, al = (d >> 2) & 63, dw = d & 3;
          int m = mt*16 + (al & 15);
          int k = c*32 + ((al >> 4) * 8) + dw*2;
          unsigned lo = bf16_rne(shB[m*LDP + k]);
          unsigned hi = bf16_rne(shB[m*LDP + k + 1]);
          af[d] = lo | (hi << 16);
        }
        __syncthreads();
        f32x4 acc = {0.f, 0.f, 0.f, 0.f};
        #pragma unroll
        for (int c = 0; c < 16; ++c){
          short8 av = *(short8*)&af[(c*64 + lane)*4];
          acc = __builtin_amdgcn_mfma_f32_16x16x32_bf16(av, bw[c], acc, 0, 0, 0);
        }
        accs[mt] = acc;
        __syncthreads();
      }
      // epilogue: D[m][n], m = mt*16 + (lane>>4)*4 + r, n = bid*128 + wave*16 + (lane&15)
      {
        int n_loc = wave*16 + (lane & 15);
        int n = bid*128 + n_loc;
        float bias = a.bout[n];
        float wn = a.wnormE[n];
        int quad = lane >> 4;
        #pragma unroll
        for (int mt = 0; mt < 2; ++mt){
          unsigned long long pk = 0ULL;
          #pragma unroll
          for (int r = 0; r < 4; ++r){
            int m = mt*16 + quad*4 + r;
            float lg = accs[mt][r] + bias;
            float mg = wn * hnormL[m];
            float lb = lg - mg;
            float ub = lg + mg;
            pk |= ((unsigned long long)bf16_ru(ub)) << (16*r);
            atomicMax(&lbmaxL[m], key32(lb));
          }
          ubq8[n_loc*8 + mt*4 + quad] = pk;   // ushort idx n_loc*32 + m
        }
      }
      __syncthreads();
      if (tid < 32) atomicMax(&a.plb[tid*32], lbmaxL[tid]);
    }
    gridbar(a.bar, bid);

    // ---- Phase D: candidate scan + exact fp32 rescore ----
    if (bid < CBLK){
      if (tid < 32) maxlbL[tid] = cload4u(&a.plb[tid*32]);
      __syncthreads();
      #pragma unroll 1
      for (int pass = 0; pass < 8; ++pass){
        if (tid == 0) candCnt = 0;
        __syncthreads();
        int idx = pass*512 + tid;           // n_loc = idx>>5, b = idx&31
        unsigned short q = ubq16[idx];
        float uf = __uint_as_float(((unsigned)q) << 16);
        if (key32(uf) >= maxlbL[idx & 31]){
          int pos = atomicAdd(&candCnt, 1);
          candList[pos] = idx;
        }
        __syncthreads();
        int nc = candCnt;
        for (int ci = wave; ci < nc; ci += 8){
          int cidx = candList[ci];
          int n_loc = cidx >> 5, b = cidx & 31;
          int n = bid*128 + n_loc;
          const float* wrow = a.Wout + (size_t)n*512 + lane*8;
          const float* hrow = shB + b*LDP + lane*8;
          float4 w0 = *(const float4*)wrow,      w1 = *(const float4*)(wrow + 4);
          float4 x0 = *(const float4*)hrow,      x1 = *(const float4*)(hrow + 4);
          float d = dot4acc(w0, x0, 0.f);
          d = dot4acc(w1, x1, d);
          d += __shfl_xor(d, 1);  d += __shfl_xor(d, 2);  d += __shfl_xor(d, 4);
          d += __shfl_xor(d, 8);  d += __shfl_xor(d, 16); d += __shfl_xor(d, 32);
          if (lane == 0){
            float lg = d + a.bout[n];
            unsigned long long key =
                (((unsigned long long)key32(lg)) << 32) | (unsigned)(~(unsigned)n);
            atomicMax(&a.packed[b*16], key);
          }
        }
        __syncthreads();
      }
    }
    gridbar(a.bar, bid);
  }

  // ---- final harvest + final hidden states ----
  if (bid == 0 && tid < Bsz){
    unsigned long long p = cload8(&a.packed[tid*16]);
    int tok = (int)(~(unsigned)(p & 0xffffffffULL));
    a.out[tid*T + (T-1)] = (float)tok;
  }
  int e = bid*NTHR + tid;
  if (e < BH/2){
    unsigned long long v0 = cload8((const unsigned long long*)h0g + e);
    unsigned long long v1 = cload8((const unsigned long long*)h1g + e);
    *((unsigned long long*)(a.out + Bsz*T) + e)      = v0;
    *((unsigned long long*)(a.out + Bsz*T + BH) + e) = v1;
  }
}

// ================= fallback (round-4 fp32 path) if ws too small =================
__global__ __launch_bounds__(NTHR, 1) void decoder_kernel_fb(Args a){
  const int tid = threadIdx.x;
  const int bid = blockIdx.x;
  const int T = a.maxn[0];
  float* h0g = a.hbuf;
  float* h1g = a.hbuf + BH;
  __shared__ float shA[Bsz*LDP];
  __shared__ float shB[Bsz*LDP];
  __shared__ unsigned long long lbest[32*32];
  __shared__ int sh_tok[Bsz];

  for (int t = 0; t < T; ++t){
    if (t == 0) stage_h(a.h0_init, shA, tid);
    if (tid < Bsz){
      int tok;
      if (t == 0) tok = 1;
      else        tok = (int)(~(unsigned)(cload8(&a.packed[tid*16]) & 0xffffffffULL));
      sh_tok[tid] = tok;
    }
    __syncthreads();
    {
      int oct = tid >> 3, lane8 = tid & 7;
      int b = oct & 31, jj = oct >> 5;
      int j = bid*2 + jj;
      const float* xrow = a.emb + (size_t)sh_tok[b] * Hsz;
      gru_oct(xrow, shA + b*LDP, a.Wih0, a.Whh0, a.bih0, a.bhh0,
              j, lane8, h0g + b*Hsz + j);
    }
    gridbar(a.bar, bid);
    if (bid == 0 && tid < Bsz){
      if (t > 0){
        unsigned long long p = cload8(&a.packed[tid*16]);
        a.out[tid*T + (t-1)] = (float)((int)(~(unsigned)(p & 0xffffffffULL)));
      }
      cstore8(&a.packed[tid*16], 0ULL);
    }
    stage_h(h0g, shA, tid);
    if (t == 0) stage_h(a.h0_init + BH, shB, tid);
    __syncthreads();
    {
      int oct = tid >> 3, lane8 = tid & 7;
      int b = oct & 31, jj = oct >> 5;
      int j = bid*2 + jj;
      gru_oct(shA + b*LDP, shB + b*LDP, a.Wih1, a.Whh1, a.bih1, a.bhh1,
              j, lane8, h1g + b*Hsz + j);
    }
    gridbar(a.bar, bid);
    stage_h(h1g, shB, tid);
    __syncthreads();
    if (bid < CBLK){
      const int quad = tid >> 2, l4 = tid & 3;
      const int rg = quad & 31, bg = quad >> 5;
      const int rowbase = bid*128 + rg*4;
      const float* wr = a.Wout + (size_t)rowbase * Hsz;
      const float* hb = shB + bg*8*LDP;
      float acc[4][8];
      #pragma unroll
      for (int s = 0; s < 4; ++s)
        #pragma unroll
        for (int j = 0; j < 8; ++j) acc[s][j] = 0.f;
      #pragma unroll 2
      for (int i = 0; i < 32; ++i){
        const int k = i*16 + l4*4;
        float4 wv[4], hv[8];
        #pragma unroll
        for (int s = 0; s < 4; ++s) wv[s] = *(const float4*)(wr + (size_t)s*Hsz + k);
        #pragma unroll
        for (int j = 0; j < 8; ++j) hv[j] = *(const float4*)(hb + j*LDP + k);
        #pragma unroll
        for (int s = 0; s < 4; ++s)
          #pragma unroll
          for (int j = 0; j < 8; ++j) acc[s][j] = dot4acc(wv[s], hv[j], acc[s][j]);
      }
      #pragma unroll
      for (int s = 0; s < 4; ++s)
        #pragma unroll
        for (int j = 0; j < 8; ++j){
          float v = acc[s][j];
          v += __shfl_xor(v, 1); v += __shfl_xor(v, 2);
          acc[s][j] = v;
        }
      if (l4 == 0){
        float4 bv = *(const float4*)(a.bout + rowbase);
        float bb[4] = {bv.x, bv.y, bv.z, bv.w};
        #pragma unroll
        for (int j = 0; j < 8; ++j){
          float best = -3.4e38f; int bi = rowbase;
          #pragma unroll
          for (int s = 0; s < 4; ++s){
            float lv = acc[s][j] + bb[s];
            if (lv > best){ best = lv; bi = rowbase + s; }
          }
          unsigned u = __float_as_uint(best);
          unsigned key = (u & 0x80000000u) ? ~u : (u | 0x80000000u);
          lbest[rg*32 + bg*8 + j] =
              ((unsigned long long)key << 32) | (unsigned)(~(unsigned)bi);
        }
      }
      __syncthreads();
      if (tid < Bsz){
        unsigned long long m = lbest[tid];
        #pragma unroll 4
        for (int r = 1; r < 32; ++r){
          unsigned long long c = lbest[r*32 + tid];
          m = (c > m) ? c : m;
        }
        atomicMax(&a.packed[tid*16], m);
      }
    }
    gridbar(a.bar, bid);
  }
  if (bid == 0 && tid < Bsz){
    unsigned long long p = cload8(&a.packed[tid*16]);
    a.out[tid*T + (T-1)] = (float)((int)(~(unsigned)(p & 0xffffffffULL)));
  }
  int e = bid*NTHR + tid;
  if (e < BH/2){
    unsigned long long v0 = cload8((const unsigned long long*)h0g + e);
    unsigned long long v1 = cload8((const unsigned long long*)h1g + e);
    *((unsigned long long*)(a.out + Bsz*T) + e)      = v0;
    *((unsigned long long*)(a.out + Bsz*T + BH) + e) = v1;
  }
}

extern "C" void kernel_launch(void* const* d_in, const int* in_sizes, int n_in,
                              void* d_out, int out_size, void* d_ws, size_t ws_size,
                              hipStream_t stream){
  Args a;
  a.h0_init = (const float*)d_in[0];
  a.emb  = (const float*)d_in[1];
  a.Wih0 = (const float*)d_in[2];
  a.Whh0 = (const float*)d_in[3];
  a.bih0 = (const float*)d_in[4];
  a.bhh0 = (const float*)d_in[5];
  a.Wih1 = (const float*)d_in[6];
  a.Whh1 = (const float*)d_in[7];
  a.bih1 = (const float*)d_in[8];
  a.bhh1 = (const float*)d_in[9];
  a.Wout = (const float*)d_in[10];
  a.bout = (const float*)d_in[11];
  a.maxn = (const int*)d_in[12];
  a.out  = (float*)d_out;
  char* wsb = (char*)d_ws;
  a.hbuf   = (float*)(wsb + WS_HBUF);
  a.packed = (unsigned long long*)(wsb + WS_PACKED);
  a.plb    = (unsigned*)(wsb + WS_PLB);
  a.bar    = (unsigned*)(wsb + WS_BAR);
  a.wpack  = (const unsigned*)(wsb + WS_WPACK);
  a.wnormE = (const float*)(wsb + WS_WNORM);

  // zero packed + plb + bar (12 KB); ws is re-poisoned 0xAA before every call
  hipMemsetAsync(wsb + WS_PACKED, 0, 12288, stream);

  void* params[] = { &a };
  if (ws_size >= (size_t)WS_NEEDED){
    repack_kernel<<<CBLK, 512, 0, stream>>>(a.Wout, (unsigned*)a.wpack, (float*)a.wnormE);
    hipLaunchCooperativeKernel((void*)decoder_kernel, dim3(NBLK), dim3(NTHR),
                               params, 0, stream);
  } else {
    hipLaunchCooperativeKernel((void*)decoder_kernel_fb, dim3(NBLK), dim3(NTHR),
                               params, 0, stream);
  }
}